// Round 20
// baseline (292.941 us; speedup 1.0000x reference)
//
#include <hip/hip_runtime.h>

// DILATE loss via the soft-DTW forward/backward identity:
//   E[i,j] = exp((V - R[i,j] - Rrev[i,j] + D[i,j]) / gamma)
// Round 20: r18 base (209us pass) with the in-loop HARDWARE TRANS OPS
// (v_exp_f32 x2, v_log_f32 x1 per cell) replaced by FMA-pipeline
// polynomials: exp2 = rndne + deg-4 Taylor + exponent-field add (args
// clamped to [-30,0] -- smaller adds <2^-30 to s>=1); log2 on s in [1,3]
// = exponent extract + sqrt2-split + deg-6 Taylor. Removes ~2 trans
// latencies (~100cy each, untested suspect) from every step's carried
// chain at the cost of ~+90cy/step issue. ereduce keeps HW exp2.

#define NSEQ 512
#define K2   144.269504088896f      // (1/gamma)*log2(e) = 100/ln2
#define SC   0.006931471805599453f  // ln2/100
#define BIGV 1e10f
#define ALPHA 0.5f
#define PACKS 327680                // floats per sample per dir (4*640*128)

// full-wave shift toward higher lanes by 1 (lane l gets lane l-1); lane 0 -> BIGV
__device__ __forceinline__ float shr1(float v) {
    return __int_as_float(__builtin_amdgcn_update_dpp(
        __float_as_int(BIGV), __float_as_int(v), 0x138 /*wave_shr:1*/,
        0xF, 0xF, false));
}

// 2^x for x <= 0 via rndne + deg-4 poly + exponent-field add (no trans ops)
__device__ __forceinline__ float fexp2(float x) {
    x = fmaxf(x, -30.0f);
    const float n = __builtin_rintf(x);      // v_rndne_f32
    const float f = x - n;                   // [-0.5, 0.5]
    float p = 0.00961813f;                   // Taylor of 2^f, err ~4e-5
    p = fmaf(p, f, 0.05550411f);
    p = fmaf(p, f, 0.24022651f);
    p = fmaf(p, f, 0.69314718f);
    p = fmaf(p, f, 1.0f);
    const int ni = (int)n;                   // integral, in [-30, 0]
    return __int_as_float(__float_as_int(p) + (int)((unsigned)ni << 23));
}

// log2(s) for s in [1, 4) via exponent extract + sqrt2-split + deg-6 poly
__device__ __forceinline__ float flog2(float s) {
    const int si = __float_as_int(s);
    float nf = (float)((si >> 23) - 127);
    float m = __int_as_float((si & 0x007fffff) | 0x3f800000);  // [1, 2)
    const bool big = (m >= 1.41421356f);
    m  = big ? 0.5f * m : m;                 // [0.7071, 1.4142)
    nf = big ? nf + 1.0f : nf;
    const float y = m - 1.0f;                // [-0.2929, 0.4142]
    float q = 0.20609929f;                   // log2(1+y)/y Taylor, err ~4e-4
    q = fmaf(q, y, -0.24044917f);
    q = fmaf(q, y, 0.28853901f);
    q = fmaf(q, y, -0.36067376f);
    q = fmaf(q, y, 0.48089835f);
    q = fmaf(q, y, -0.72134752f);
    q = fmaf(q, y, 1.44269504f);
    return fmaf(q, y, nf);
}

__global__ __launch_bounds__(256, 1) void sdtw_pass(
    const float* __restrict__ outp, const float* __restrict__ targ,
    float* __restrict__ slabA, float* __restrict__ slabB,
    float* __restrict__ vals, float* __restrict__ vraw, int kbase)
{
    const int tid = threadIdx.x;
    const int w = tid >> 6, l = tid & 63;
    const int i0 = 128 * w + 2 * l;          // lane owns rows i0, i0+1
    const int dir = blockIdx.x & 1;
    const int kk  = blockIdx.x >> 1;
    const int k   = kbase + kk;
    const bool lane0 = (l == 0), lane63 = (l == 63);

    __shared__ float o_pad[644];   // o[j] at [j+1], pads 0
    __shared__ float t_sh[516];
    __shared__ float Rbf[3][644];  // boundary row 128(w+1)-1 by column (col c at [c+1])
    __shared__ float dummyF[644];  // virtual row -1: [0]=0 (R[-1,-1]), else BIG

    for (int q = tid; q < 644; q += 256) { o_pad[q] = 0.f; dummyF[q] = BIGV; }
    for (int q = tid; q < 516; q += 256) t_sh[q] = 0.f;
    __syncthreads();
    if (tid == 0) {
        dummyF[0] = 0.f;                     // virtual R[-1,-1] = 0
        Rbf[0][0] = BIGV; Rbf[1][0] = BIGV; Rbf[2][0] = BIGV;
    }
    for (int q = tid; q < NSEQ; q += 256) {  // dir 1: reversed sequences
        const int src = dir ? (NSEQ - 1 - q) : q;
        o_pad[1 + q] = outp[(size_t)k * NSEQ + src];
        t_sh[q]      = targ[(size_t)k * NSEQ + src];
    }
    __syncthreads();

    const float t0 = t_sh[i0], t1 = t_sh[i0 + 1];
    const float* RbfR = (w == 0) ? dummyF : Rbf[w - 1];
    float*       RbfW = Rbf[w < 3 ? w : 2];          // guarded by (w<3)

    float2* __restrict__ sp2 =
        (float2*)((dir ? slabB : slabA) + (size_t)kk * PACKS) + w * 40960 + l;

    float rp1_0 = BIGV, rp1_1 = BIGV, rp2_0 = BIGV, rp2_1 = BIGV;
    float sbv = BIGV;                        // carried shr1(rp1_1) == previous sA
    float rfinal = BIGV;

// batched group load: 8 o-values + 8 boundary values into named regs
#define LOADG(OQ, BQ, GB)                                                 \
    _Pragma("unroll") for (int q = 0; q < 8; ++q) {                       \
        const int jj = jw0 + (GB) + q;                                    \
        const int ob = (jj > 0) ? jj : 0;                                 \
        OQ[q] = o_pad[ob + 1];                                            \
        BQ[q] = RbfR[ob + 1];                                             \
    }

// 8-step chain group; stores + boundary export batched at group end
#define BODYG(OQ, BQ, STQ, GB)                                            \
    _Pragma("unroll") for (int q = 0; q < 8; ++q) {                       \
        const int jj = jw0 + (GB) + q;                                    \
        const float oj  = OQ[q];                                          \
        const float ojm = ojmc;                                           \
        const float bdA = BQ[q];                                          \
        const float bdB = bdBc;                                           \
        const float sA = shr1(rp1_1);                                     \
        const float sB = sbv;                                             \
        const float a0 = lane0 ? bdA : sA;                                \
        const float b0 = lane0 ? bdB : sB;                                \
        const float c0 = rp1_0;                                           \
        float mn0 = fminf(fminf(a0, b0), c0);                             \
        float mx0 = fmaxf(fmaxf(a0, b0), c0);                             \
        float md0 = __builtin_amdgcn_fmed3f(a0, b0, c0);                  \
        float s0 = 1.0f + fexp2(mn0 - md0) + fexp2(mn0 - mx0);            \
        float sm0 = mn0 - flog2(s0);                                      \
        float dv0 = t0 - oj;                                              \
        float r0v = fmaf(dv0 * dv0, K2, sm0);                             \
        float mn1 = fminf(fminf(rp1_0, rp2_0), rp1_1);                    \
        float mx1 = fmaxf(fmaxf(rp1_0, rp2_0), rp1_1);                    \
        float md1 = __builtin_amdgcn_fmed3f(rp1_0, rp2_0, rp1_1);         \
        float s1 = 1.0f + fexp2(mn1 - md1) + fexp2(mn1 - mx1);            \
        float sm1 = mn1 - flog2(s1);                                      \
        float dv1 = t1 - ojm;                                             \
        float r1v = fmaf(dv1 * dv1, K2, sm1);                             \
        const bool act0 = ((unsigned)jj < 512u);                          \
        const bool act1 = ((unsigned)(jj - 1) < 512u);                    \
        const float r0n = act0 ? r0v : BIGV;                              \
        const float r1n = act1 ? r1v : BIGV;                              \
        rp2_0 = rp1_0; rp1_0 = r0n;                                       \
        rp2_1 = rp1_1; rp1_1 = r1n;                                       \
        sbv = sA; ojmc = oj; bdBc = bdA;                                  \
        STQ[q] = make_float2(r0v, r1v);                                   \
    }                                                                     \
    _Pragma("unroll") for (int q = 0; q < 8; ++q)                         \
        spw[((GB) + q) * 64] = STQ[q];                                    \
    if (lane63 && w < 3) {                                                \
        _Pragma("unroll") for (int q = 0; q < 8; ++q) {                   \
            const int jj = jw0 + (GB) + q;                                \
            if ((unsigned)(jj - 1) < 512u) RbfW[jj] = STQ[q].y;           \
        }                                                                 \
    }

    for (int ss = 0; ss < 19; ++ss) {
        const int mw = ss - 3 * w;               // wave-local window
        if (0 <= mw && mw < 10) {
            const int tb = (mw + 2 * w) * 64;    // global diag base
            const int jw0 = tb - i0;             // column of r=0 cell at u=0
            float2* __restrict__ spw = sp2 + (size_t)(mw * 64) * 64;
            const int ob0 = (jw0 > 0) ? jw0 : 0;
            float ojmc = o_pad[ob0];             // o[jw0-1] (pad 0 / clamp)
            float bdBc = RbfR[ob0];              // R[i0-1, jw0-1] (sentinel/virtual)
            float oqA[8], bqA[8], oqB[8], bqB[8];
            float2 stqA[8], stqB[8];
            LOADG(oqA, bqA, 0)
            for (int gp = 0; gp < 3; ++gp) {     // runtime loop: I-cache-sized body
                const int gb = gp * 16;
                LOADG(oqB, bqB, gb + 8)
                BODYG(oqA, bqA, stqA, gb)
                LOADG(oqA, bqA, gb + 16)
                BODYG(oqB, bqB, stqB, gb + 8)
            }
            LOADG(oqB, bqB, 56)
            BODYG(oqA, bqA, stqA, 48)
            BODYG(oqB, bqB, stqB, 56)
            if (mw == 9 && w == 3) rfinal = stqB[6].y;   // cell (511,511): u=62
        }
        asm volatile("s_waitcnt lgkmcnt(0)\n\ts_barrier" ::: "memory");
    }
    if (w == 3 && lane63 && dir == 0) { vals[k] = rfinal * SC; vraw[k] = rfinal; }
#undef LOADG
#undef BODYG
}

// ---------------- pointwise E map-reduce ----------------
// E[i,j] = exp2(Vraw - A[i,j] - B[i',j'] + D[i,j]*K2); acc += E*(i-j)^2,
// with (i',j') = (511-i, 511-j) in the reverse pass's skewed layout.
// float offset of cell (i,j): (i>>7)*65536 + (i+j)*128 + (i&127).
__global__ __launch_bounds__(256) void ereduce(
    const float* __restrict__ outp, const float* __restrict__ targ,
    const float* __restrict__ slabA, const float* __restrict__ slabB,
    const float* __restrict__ vraw, float* __restrict__ spart, int kbase)
{
    const int tid = threadIdx.x;
    const int sect = blockIdx.x & 15;
    const int kk = blockIdx.x >> 4;
    const int k = kbase + kk;

    __shared__ float t_sh[NSEQ], o_sh[NSEQ];
    __shared__ float red[4];
    for (int q = tid; q < NSEQ; q += 256) {
        t_sh[q] = targ[(size_t)k * NSEQ + q];
        o_sh[q] = outp[(size_t)k * NSEQ + q];
    }
    __syncthreads();

    const float* __restrict__ A  = slabA + (size_t)kk * PACKS;
    const float* __restrict__ Bs = slabB + (size_t)kk * PACKS;
    const float V = vraw[k];
    float acc = 0.f;
    const int dend = (sect == 15) ? 1023 : (sect * 64 + 64);
    for (int d = sect * 64; d < dend; ++d) {
        const int ilo = (d > 511) ? (d - 511) : 0;
        const int ihi = (d < 512) ? d : 511;
        const int dbA = d * 128;
        const int dbB = (1022 - d) * 128;
        for (int i = ilo + tid; i <= ihi; i += 256) {
            const int i2 = 511 - i;
            const float a = A [((i  >> 7) << 16) + dbA + (i  & 127)];
            const float b = Bs[((i2 >> 7) << 16) + dbB + (i2 & 127)];
            const float dv = t_sh[i] - o_sh[d - i];
            const float arg = fmaf(dv * dv, K2, V - a - b);
            const float E = __builtin_exp2f(arg);       // in [0, 1+eps]
            const float df = (float)(2 * i - d);        // i - j
            acc = fmaf(E * df, df, acc);
        }
    }
    for (int off = 32; off; off >>= 1) acc += __shfl_down(acc, off);
    if ((tid & 63) == 0) red[tid >> 6] = acc;
    __syncthreads();
    if (tid == 0) spart[k * 16 + sect] = red[0] + red[1] + red[2] + red[3];
}

__global__ void finalize_kernel(const float* __restrict__ vals,
                                const float* __restrict__ spart,
                                float* __restrict__ out, int B) {
    int t = threadIdx.x;    // 64 threads
    float v = 0.0f, s = 0.0f;
    for (int q = t; q < B; q += 64) v += vals[q];
    for (int q = t; q < 16 * B; q += 64) s += spart[q];
    for (int off = 32; off; off >>= 1) { v += __shfl_down(v, off); s += __shfl_down(s, off); }
    if (t == 0) {
        float loss_shape = v / (float)B;
        float loss_temporal = (s / (float)B) / ((float)NSEQ * (float)NSEQ);
        out[0] = ALPHA * loss_shape + (1.0f - ALPHA) * loss_temporal;
    }
}

extern "C" void kernel_launch(void* const* d_in, const int* in_sizes, int n_in,
                              void* d_out, int out_size, void* d_ws, size_t ws_size,
                              hipStream_t stream) {
    const float* outputs = (const float*)d_in[0];
    const float* targets = (const float*)d_in[1];
    const int B = in_sizes[0] / NSEQ;    // 64

    // ws: [0,256B) vals, [256,512B) vraw, [512,4608B) spart, [8192, ...) slabs
    float* vals  = (float*)d_ws;
    float* vraw  = vals + 64;
    float* spart = vals + 128;
    float* slabs = (float*)((char*)d_ws + 8192);

    const size_t per_sample = 2 * (size_t)PACKS * sizeof(float);   // 2.5 MiB (A+B)
    size_t avail = (ws_size > 8192) ? (ws_size - 8192) / per_sample : 0;
    int G = (int)((avail < (size_t)B) ? avail : (size_t)B);
    if (G < 1) G = 1;
    float* slabA = slabs;
    float* slabB = slabs + (size_t)G * PACKS;

    for (int kb = 0; kb < B; kb += G) {
        int g = (B - kb < G) ? (B - kb) : G;
        sdtw_pass<<<dim3(2 * g), dim3(256), 0, stream>>>(
            outputs, targets, slabA, slabB, vals, vraw, kb);
        ereduce<<<dim3(16 * g), dim3(256), 0, stream>>>(
            outputs, targets, slabA, slabB, vraw, spart, kb);
    }
    finalize_kernel<<<dim3(1), dim3(64), 0, stream>>>(vals, spart, (float*)d_out, B);
}

// Round 21
// 267.940 us; speedup vs baseline: 1.0933x; 1.0933x over previous
//
#include <hip/hip_runtime.h>

// DILATE loss via the soft-DTW forward/backward identity:
//   E[i,j] = exp((V - R[i,j] - Rrev[i,j] + D[i,j]) / gamma)
// FINAL (r18 revert, session best ~269-271us):
//  - two independent 4-wave lag-3 wavefront passes (dir0: R, dir1: Rrev)
//    as separate blocks (128 blocks), 2 rows/lane, CC=64 supersteps
//  - DPP wave_shr:1 cross-lane (no ds_bpermute), register carries
//  - per-group (8-step) batched LDS prefetch of o/boundary (r17 win)
//  - branch-free skewed float2 stores, grouped 8-at-a-time (r14+r16 wins)
//  - boundary export batched per group; runtime loop keeps I-cache small
//  - ereduce: pointwise E map-reduce at HBM rate; finalize: single wave
// Scaled domain R'' = R * (100/ln2) so softmin uses raw exp2/log2.

#define NSEQ 512
#define K2   144.269504088896f      // (1/gamma)*log2(e) = 100/ln2
#define SC   0.006931471805599453f  // ln2/100
#define BIGV 1e10f
#define ALPHA 0.5f
#define PACKS 327680                // floats per sample per dir (4*640*128)

// full-wave shift toward higher lanes by 1 (lane l gets lane l-1); lane 0 -> BIGV
__device__ __forceinline__ float shr1(float v) {
    return __int_as_float(__builtin_amdgcn_update_dpp(
        __float_as_int(BIGV), __float_as_int(v), 0x138 /*wave_shr:1*/,
        0xF, 0xF, false));
}

__global__ __launch_bounds__(256, 1) void sdtw_pass(
    const float* __restrict__ outp, const float* __restrict__ targ,
    float* __restrict__ slabA, float* __restrict__ slabB,
    float* __restrict__ vals, float* __restrict__ vraw, int kbase)
{
    const int tid = threadIdx.x;
    const int w = tid >> 6, l = tid & 63;
    const int i0 = 128 * w + 2 * l;          // lane owns rows i0, i0+1
    const int dir = blockIdx.x & 1;
    const int kk  = blockIdx.x >> 1;
    const int k   = kbase + kk;
    const bool lane0 = (l == 0), lane63 = (l == 63);

    __shared__ float o_pad[644];   // o[j] at [j+1], pads 0
    __shared__ float t_sh[516];
    __shared__ float Rbf[3][644];  // boundary row 128(w+1)-1 by column (col c at [c+1])
    __shared__ float dummyF[644];  // virtual row -1: [0]=0 (R[-1,-1]), else BIG

    for (int q = tid; q < 644; q += 256) { o_pad[q] = 0.f; dummyF[q] = BIGV; }
    for (int q = tid; q < 516; q += 256) t_sh[q] = 0.f;
    __syncthreads();
    if (tid == 0) {
        dummyF[0] = 0.f;                     // virtual R[-1,-1] = 0
        Rbf[0][0] = BIGV; Rbf[1][0] = BIGV; Rbf[2][0] = BIGV;
    }
    for (int q = tid; q < NSEQ; q += 256) {  // dir 1: reversed sequences
        const int src = dir ? (NSEQ - 1 - q) : q;
        o_pad[1 + q] = outp[(size_t)k * NSEQ + src];
        t_sh[q]      = targ[(size_t)k * NSEQ + src];
    }
    __syncthreads();

    const float t0 = t_sh[i0], t1 = t_sh[i0 + 1];
    const float* RbfR = (w == 0) ? dummyF : Rbf[w - 1];
    float*       RbfW = Rbf[w < 3 ? w : 2];          // guarded by (w<3)

    float2* __restrict__ sp2 =
        (float2*)((dir ? slabB : slabA) + (size_t)kk * PACKS) + w * 40960 + l;

    float rp1_0 = BIGV, rp1_1 = BIGV, rp2_0 = BIGV, rp2_1 = BIGV;
    float sbv = BIGV;                        // carried shr1(rp1_1) == previous sA
    float rfinal = BIGV;

// batched group load: 8 o-values + 8 boundary values into named regs
#define LOADG(OQ, BQ, GB)                                                 \
    _Pragma("unroll") for (int q = 0; q < 8; ++q) {                       \
        const int jj = jw0 + (GB) + q;                                    \
        const int ob = (jj > 0) ? jj : 0;                                 \
        OQ[q] = o_pad[ob + 1];                                            \
        BQ[q] = RbfR[ob + 1];                                             \
    }

// 8-step chain group; stores + boundary export batched at group end
#define BODYG(OQ, BQ, STQ, GB)                                            \
    _Pragma("unroll") for (int q = 0; q < 8; ++q) {                       \
        const int jj = jw0 + (GB) + q;                                    \
        const float oj  = OQ[q];                                          \
        const float ojm = ojmc;                                           \
        const float bdA = BQ[q];                                          \
        const float bdB = bdBc;                                           \
        const float sA = shr1(rp1_1);                                     \
        const float sB = sbv;                                             \
        const float a0 = lane0 ? bdA : sA;                                \
        const float b0 = lane0 ? bdB : sB;                                \
        const float c0 = rp1_0;                                           \
        float mn0 = fminf(fminf(a0, b0), c0);                             \
        float mx0 = fmaxf(fmaxf(a0, b0), c0);                             \
        float md0 = __builtin_amdgcn_fmed3f(a0, b0, c0);                  \
        float s0 = 1.0f + __builtin_exp2f(mn0 - md0)                      \
                        + __builtin_exp2f(mn0 - mx0);                     \
        float sm0 = mn0 - __builtin_log2f(s0);                            \
        float dv0 = t0 - oj;                                              \
        float r0v = fmaf(dv0 * dv0, K2, sm0);                             \
        float mn1 = fminf(fminf(rp1_0, rp2_0), rp1_1);                    \
        float mx1 = fmaxf(fmaxf(rp1_0, rp2_0), rp1_1);                    \
        float md1 = __builtin_amdgcn_fmed3f(rp1_0, rp2_0, rp1_1);         \
        float s1 = 1.0f + __builtin_exp2f(mn1 - md1)                      \
                        + __builtin_exp2f(mn1 - mx1);                     \
        float sm1 = mn1 - __builtin_log2f(s1);                            \
        float dv1 = t1 - ojm;                                             \
        float r1v = fmaf(dv1 * dv1, K2, sm1);                             \
        const bool act0 = ((unsigned)jj < 512u);                          \
        const bool act1 = ((unsigned)(jj - 1) < 512u);                    \
        const float r0n = act0 ? r0v : BIGV;                              \
        const float r1n = act1 ? r1v : BIGV;                              \
        rp2_0 = rp1_0; rp1_0 = r0n;                                       \
        rp2_1 = rp1_1; rp1_1 = r1n;                                       \
        sbv = sA; ojmc = oj; bdBc = bdA;                                  \
        STQ[q] = make_float2(r0v, r1v);                                   \
    }                                                                     \
    _Pragma("unroll") for (int q = 0; q < 8; ++q)                         \
        spw[((GB) + q) * 64] = STQ[q];                                    \
    if (lane63 && w < 3) {                                                \
        _Pragma("unroll") for (int q = 0; q < 8; ++q) {                   \
            const int jj = jw0 + (GB) + q;                                \
            if ((unsigned)(jj - 1) < 512u) RbfW[jj] = STQ[q].y;           \
        }                                                                 \
    }

    for (int ss = 0; ss < 19; ++ss) {
        const int mw = ss - 3 * w;               // wave-local window
        if (0 <= mw && mw < 10) {
            const int tb = (mw + 2 * w) * 64;    // global diag base
            const int jw0 = tb - i0;             // column of r=0 cell at u=0
            float2* __restrict__ spw = sp2 + (size_t)(mw * 64) * 64;
            const int ob0 = (jw0 > 0) ? jw0 : 0;
            float ojmc = o_pad[ob0];             // o[jw0-1] (pad 0 / clamp)
            float bdBc = RbfR[ob0];              // R[i0-1, jw0-1] (sentinel/virtual)
            float oqA[8], bqA[8], oqB[8], bqB[8];
            float2 stqA[8], stqB[8];
            LOADG(oqA, bqA, 0)
            for (int gp = 0; gp < 3; ++gp) {     // runtime loop: I-cache-sized body
                const int gb = gp * 16;
                LOADG(oqB, bqB, gb + 8)
                BODYG(oqA, bqA, stqA, gb)
                LOADG(oqA, bqA, gb + 16)
                BODYG(oqB, bqB, stqB, gb + 8)
            }
            LOADG(oqB, bqB, 56)
            BODYG(oqA, bqA, stqA, 48)
            BODYG(oqB, bqB, stqB, 56)
            if (mw == 9 && w == 3) rfinal = stqB[6].y;   // cell (511,511): u=62
        }
        asm volatile("s_waitcnt lgkmcnt(0)\n\ts_barrier" ::: "memory");
    }
    if (w == 3 && lane63 && dir == 0) { vals[k] = rfinal * SC; vraw[k] = rfinal; }
#undef LOADG
#undef BODYG
}

// ---------------- pointwise E map-reduce ----------------
// E[i,j] = exp2(Vraw - A[i,j] - B[i',j'] + D[i,j]*K2); acc += E*(i-j)^2,
// with (i',j') = (511-i, 511-j) in the reverse pass's skewed layout.
// float offset of cell (i,j): (i>>7)*65536 + (i+j)*128 + (i&127).
__global__ __launch_bounds__(256) void ereduce(
    const float* __restrict__ outp, const float* __restrict__ targ,
    const float* __restrict__ slabA, const float* __restrict__ slabB,
    const float* __restrict__ vraw, float* __restrict__ spart, int kbase)
{
    const int tid = threadIdx.x;
    const int sect = blockIdx.x & 15;
    const int kk = blockIdx.x >> 4;
    const int k = kbase + kk;

    __shared__ float t_sh[NSEQ], o_sh[NSEQ];
    __shared__ float red[4];
    for (int q = tid; q < NSEQ; q += 256) {
        t_sh[q] = targ[(size_t)k * NSEQ + q];
        o_sh[q] = outp[(size_t)k * NSEQ + q];
    }
    __syncthreads();

    const float* __restrict__ A  = slabA + (size_t)kk * PACKS;
    const float* __restrict__ Bs = slabB + (size_t)kk * PACKS;
    const float V = vraw[k];
    float acc = 0.f;
    const int dend = (sect == 15) ? 1023 : (sect * 64 + 64);
    for (int d = sect * 64; d < dend; ++d) {
        const int ilo = (d > 511) ? (d - 511) : 0;
        const int ihi = (d < 512) ? d : 511;
        const int dbA = d * 128;
        const int dbB = (1022 - d) * 128;
        for (int i = ilo + tid; i <= ihi; i += 256) {
            const int i2 = 511 - i;
            const float a = A [((i  >> 7) << 16) + dbA + (i  & 127)];
            const float b = Bs[((i2 >> 7) << 16) + dbB + (i2 & 127)];
            const float dv = t_sh[i] - o_sh[d - i];
            const float arg = fmaf(dv * dv, K2, V - a - b);
            const float E = __builtin_exp2f(arg);       // in [0, 1+eps]
            const float df = (float)(2 * i - d);        // i - j
            acc = fmaf(E * df, df, acc);
        }
    }
    for (int off = 32; off; off >>= 1) acc += __shfl_down(acc, off);
    if ((tid & 63) == 0) red[tid >> 6] = acc;
    __syncthreads();
    if (tid == 0) spart[k * 16 + sect] = red[0] + red[1] + red[2] + red[3];
}

__global__ void finalize_kernel(const float* __restrict__ vals,
                                const float* __restrict__ spart,
                                float* __restrict__ out, int B) {
    int t = threadIdx.x;    // 64 threads
    float v = 0.0f, s = 0.0f;
    for (int q = t; q < B; q += 64) v += vals[q];
    for (int q = t; q < 16 * B; q += 64) s += spart[q];
    for (int off = 32; off; off >>= 1) { v += __shfl_down(v, off); s += __shfl_down(s, off); }
    if (t == 0) {
        float loss_shape = v / (float)B;
        float loss_temporal = (s / (float)B) / ((float)NSEQ * (float)NSEQ);
        out[0] = ALPHA * loss_shape + (1.0f - ALPHA) * loss_temporal;
    }
}

extern "C" void kernel_launch(void* const* d_in, const int* in_sizes, int n_in,
                              void* d_out, int out_size, void* d_ws, size_t ws_size,
                              hipStream_t stream) {
    const float* outputs = (const float*)d_in[0];
    const float* targets = (const float*)d_in[1];
    const int B = in_sizes[0] / NSEQ;    // 64

    // ws: [0,256B) vals, [256,512B) vraw, [512,4608B) spart, [8192, ...) slabs
    float* vals  = (float*)d_ws;
    float* vraw  = vals + 64;
    float* spart = vals + 128;
    float* slabs = (float*)((char*)d_ws + 8192);

    const size_t per_sample = 2 * (size_t)PACKS * sizeof(float);   // 2.5 MiB (A+B)
    size_t avail = (ws_size > 8192) ? (ws_size - 8192) / per_sample : 0;
    int G = (int)((avail < (size_t)B) ? avail : (size_t)B);
    if (G < 1) G = 1;
    float* slabA = slabs;
    float* slabB = slabs + (size_t)G * PACKS;

    for (int kb = 0; kb < B; kb += G) {
        int g = (B - kb < G) ? (B - kb) : G;
        sdtw_pass<<<dim3(2 * g), dim3(256), 0, stream>>>(
            outputs, targets, slabA, slabB, vals, vraw, kb);
        ereduce<<<dim3(16 * g), dim3(256), 0, stream>>>(
            outputs, targets, slabA, slabB, vraw, spart, kb);
    }
    finalize_kernel<<<dim3(1), dim3(64), 0, stream>>>(vals, spart, (float*)d_out, B);
}